// Round 1
// baseline (3745.579 us; speedup 1.0000x reference)
//
#include <hip/hip_runtime.h>
#include <math.h>

#define DEV __device__ __forceinline__

static constexpr int B_ = 128, T_ = 32, H_ = 512;
static constexpr int S_ = 2048, M_ = 64, OUT_ = 256;
static constexpr int VC_ = 712;   // 256 (vt) + 453 (ctrl), padded to 712
static constexpr float EPSF = 1e-8f;

DEV float sigmoidf_(float x){ return 1.0f/(1.0f+expf(-x)); }
DEV float softplusf_(float x){ return fmaxf(x,0.0f) + log1pf(expf(-fabsf(x))); }

// ---------------- preamble: mem [B,S,M] -> memT [B,M,S] ----------------
__global__ __launch_bounds__(256)
void k_transpose_mem(const float* __restrict__ mem, float* __restrict__ memT){
  const int b = blockIdx.x, sc = blockIdx.y;   // sc < 64 (32-slot chunks)
  __shared__ float tile[32*65];
  const float* src = mem + ((size_t)b*S_ + (size_t)sc*32)*M_;
  #pragma unroll
  for(int p=0;p<8;p++){
    int idx = threadIdx.x + p*256;     // 0..2047 = i*64+m
    int i = idx>>6, m = idx&63;
    tile[i*65+m] = src[idx];
  }
  __syncthreads();
  float* dst = memT + (size_t)b*M_*S_ + (size_t)sc*32;
  #pragma unroll
  for(int p=0;p<8;p++){
    int idx = threadIdx.x + p*256;
    int m = idx>>5, i = idx&31;
    dst[(size_t)m*S_ + i] = tile[i*65+m];
  }
}

// ---------------- preamble: W_rd [256,256] -> W_rdT ----------------
__global__ __launch_bounds__(256)
void k_transpose_rd(const float* __restrict__ W, float* __restrict__ WT){
  int idx = blockIdx.x*256 + threadIdx.x;  // 65536
  int k = idx>>8, o = idx&255;
  WT[k*256+o] = W[o*256+k];
}

// ---------------- generic fp32 GEMM  C[M,N] = A[M,K] * Bm[N,K]^T ----------------
// 64x64 tile, BK=16, 256 threads, 4x4 micro-tile. Optional split-K via blockIdx.z
// (each split writes its own C plane at z*Mtot*ldc). Optional bias (bias0+bias1).
__global__ __launch_bounds__(256)
void k_gemm64(const float* __restrict__ A, int lda,
              const float* __restrict__ Bm, int ldb,
              float* __restrict__ C, int ldc,
              int kCount,
              const float* __restrict__ bias0, const float* __restrict__ bias1)
{
  const int BM=64, BN=64, BK=16;
  __shared__ float As[BK*BM];
  __shared__ float Bs[BK*BN];
  const int m0 = blockIdx.x*BM, n0 = blockIdx.y*BN;
  const int tid = threadIdx.x;
  const int tx = tid & 15, ty = tid >> 4;
  const int kStart = blockIdx.z * kCount;
  float acc[4][4] = {};
  const int row = tid >> 2, kk = (tid & 3) * 4;
  for(int k0 = kStart; k0 < kStart + kCount; k0 += BK){
    float4 av = *(const float4*)(A  + (size_t)(m0+row)*lda + k0 + kk);
    float4 bv = *(const float4*)(Bm + (size_t)(n0+row)*ldb + k0 + kk);
    As[(kk+0)*BM+row]=av.x; As[(kk+1)*BM+row]=av.y; As[(kk+2)*BM+row]=av.z; As[(kk+3)*BM+row]=av.w;
    Bs[(kk+0)*BN+row]=bv.x; Bs[(kk+1)*BN+row]=bv.y; Bs[(kk+2)*BN+row]=bv.z; Bs[(kk+3)*BN+row]=bv.w;
    __syncthreads();
    #pragma unroll
    for(int k=0;k<BK;k++){
      float4 a = *(const float4*)&As[k*BM + 4*ty];
      float4 b = *(const float4*)&Bs[k*BN + 4*tx];
      acc[0][0]+=a.x*b.x; acc[0][1]+=a.x*b.y; acc[0][2]+=a.x*b.z; acc[0][3]+=a.x*b.w;
      acc[1][0]+=a.y*b.x; acc[1][1]+=a.y*b.y; acc[1][2]+=a.y*b.z; acc[1][3]+=a.y*b.w;
      acc[2][0]+=a.z*b.x; acc[2][1]+=a.z*b.y; acc[2][2]+=a.z*b.z; acc[2][3]+=a.z*b.w;
      acc[3][0]+=a.w*b.x; acc[3][1]+=a.w*b.y; acc[3][2]+=a.w*b.z; acc[3][3]+=a.w*b.w;
    }
    __syncthreads();
  }
  float* Cz = C + (size_t)blockIdx.z * (size_t)gridDim.x * BM * (size_t)ldc;
  #pragma unroll
  for(int i=0;i<4;i++){
    int m = m0 + 4*ty + i;
    int n = n0 + 4*tx;
    float4 o; o.x=acc[i][0]; o.y=acc[i][1]; o.z=acc[i][2]; o.w=acc[i][3];
    if(bias0){
      o.x += bias0[n]+bias1[n];     o.y += bias0[n+1]+bias1[n+1];
      o.z += bias0[n+2]+bias1[n+2]; o.w += bias0[n+3]+bias1[n+3];
    }
    *(float4*)(Cz + (size_t)m*ldc + n) = o;
  }
}

// ---------------- per-step: LSTM elementwise (sums split-K partials + xg) ----------------
__global__ __launch_bounds__(256)
void k_lstm(const float* __restrict__ xg, const float* __restrict__ gp,
            float* __restrict__ h, float* __restrict__ c, int t)
{
  int idx = blockIdx.x*256 + threadIdx.x;   // 65536 = 128*512
  int b = idx >> 9, j = idx & 511;
  const float* xr = xg + ((size_t)b*T_ + t)*(size_t)(4*H_);
  float gi = xr[j], gf = xr[512+j], gg = xr[1024+j], go = xr[1536+j];
  #pragma unroll
  for(int s4=0;s4<4;s4++){
    const float* pr = gp + ((size_t)s4*B_ + b)*(size_t)(4*H_);
    gi += pr[j]; gf += pr[512+j]; gg += pr[1024+j]; go += pr[1536+j];
  }
  float cc = sigmoidf_(gf)*c[idx] + sigmoidf_(gi)*tanhf(gg);
  float hh = sigmoidf_(go)*tanhf(cc);
  c[idx] = cc; h[idx] = hh;
}

// ---------------- per-step: vt+ctrl GEMM  [128,712] = h[128,512] @ cat(W_out,W_head)^T ----------------
__global__ __launch_bounds__(256)
void k_vtctrl(const float* __restrict__ h, const float* __restrict__ Wout,
              const float* __restrict__ bout, const float* __restrict__ Whead,
              const float* __restrict__ bhead, float* __restrict__ vc)
{
  const int BM=32, BN=32, BK=16;
  __shared__ float As[BK*BM], Bs[BK*BN];
  const int m0 = blockIdx.x*BM, n0 = blockIdx.y*BN;
  const int tid = threadIdx.x, tx = tid&15, ty = tid>>4;
  float acc[2][2] = {};
  for(int k0=0;k0<512;k0+=BK){
    #pragma unroll
    for(int p=0;p<2;p++){
      int idx = tid + p*256;            // 512 elems
      int r = idx>>4, kq = idx&15;
      As[kq*BM+r] = h[(size_t)(m0+r)*512 + k0+kq];
      int j = n0 + r;
      float v = 0.f;
      if(j < 256)      v = Wout[(size_t)j*512 + k0+kq];
      else if(j < 709) v = Whead[(size_t)(j-256)*512 + k0+kq];
      Bs[kq*BN+r] = v;
    }
    __syncthreads();
    #pragma unroll
    for(int k=0;k<BK;k++){
      float2 a = *(const float2*)&As[k*BM + 2*ty];
      float2 b = *(const float2*)&Bs[k*BN + 2*tx];
      acc[0][0]+=a.x*b.x; acc[0][1]+=a.x*b.y; acc[1][0]+=a.y*b.x; acc[1][1]+=a.y*b.y;
    }
    __syncthreads();
  }
  #pragma unroll
  for(int i=0;i<2;i++){
    int m = m0 + 2*ty + i;
    #pragma unroll
    for(int j2=0;j2<2;j2++){
      int n = n0 + 2*tx + j2;
      if(n < VC_){
        float bv = 0.f;
        if(n < 256) bv = bout[n]; else if(n < 709) bv = bhead[n-256];
        vc[(size_t)m*VC_ + n] = (n < 709) ? acc[i][j2] + bv : 0.f;
      }
    }
  }
}

// ---------------- per-step: all 5 heads' logits over OLD mem ----------------
// scores[b][head][s], head 0..3 = read heads, head 4 = write head. Final logits
// (beta * cossim) — beta/||k|| folded into one coefficient.
__global__ __launch_bounds__(256)
void k_scores(const float* __restrict__ memT, const float* __restrict__ vc,
              float* __restrict__ scores)
{
  __shared__ float kk[5*64];
  __shared__ float coef[5];
  const int b = blockIdx.x, ch = blockIdx.y, tid = threadIdx.x;
  const float* v = vc + (size_t)b*VC_;
  kk[tid] = tanhf(v[256+tid]);                 // kr (256)
  if(tid < 64) kk[256+tid] = tanhf(v[516+tid]);// kw (64)
  __syncthreads();
  if(tid < 5){
    float s = 0.f;
    for(int m=0;m<64;m++){ float x = kk[tid*64+m]; s += x*x; }
    float beta = softplusf_( tid<4 ? v[512+tid] : v[580] );
    coef[tid] = beta / fmaxf(sqrtf(s), EPSF);
  }
  __syncthreads();
  const int s = ch*256 + tid;
  const float* mb = memT + (size_t)b*(size_t)(M_*S_) + s;
  float nrm=0.f, d0=0.f, d1=0.f, d2=0.f, d3=0.f, dw=0.f;
  #pragma unroll 8
  for(int m=0;m<64;m++){
    float x = mb[(size_t)m*S_];
    nrm += x*x;
    d0 += x*kk[m];     d1 += x*kk[64+m]; d2 += x*kk[128+m];
    d3 += x*kk[192+m]; dw += x*kk[256+m];
  }
  float inv = 1.0f / fmaxf(sqrtf(nrm), EPSF);
  float* sc = scores + (size_t)b*5*(size_t)S_ + s;
  sc[0*S_] = coef[0]*d0*inv;
  sc[1*S_] = coef[1]*d1*inv;
  sc[2*S_] = coef[2]*d2*inv;
  sc[3*S_] = coef[3]*d3*inv;
  sc[4*S_] = coef[4]*dw*inv;
}

// ---------------- per-step: write head + mem update + read heads + output ----------------
__global__ __launch_bounds__(256)
void k_heads(float* __restrict__ memT,
             const float* __restrict__ scores,
             const float* __restrict__ vc,
             const float* __restrict__ WrdT,
             const float* __restrict__ b_rd,
             float* __restrict__ out, int t)
{
  __shared__ float kr[256];
  __shared__ float er[64], ad[64];
  __shared__ float coefR[4];
  __shared__ float nv[8*64];
  __shared__ int   widx[8];
  __shared__ float wval[8];
  __shared__ float fix[4*8];
  __shared__ float readsv[256];

  const int b = blockIdx.x, tid = threadIdx.x;
  const int lane = tid & 63, wave = tid >> 6;
  const float* v = vc + (size_t)b*VC_;

  // phase 1: parameter transforms
  kr[tid] = tanhf(v[256+tid]);
  if(tid < 64){ er[tid] = sigmoidf_(v[581+tid]); ad[tid] = tanhf(v[645+tid]); }
  __syncthreads();

  // phase 2: write-head softmax stats + top-8 (wave 0); coefR (wave 1)
  if(wave == 1 && lane < 4){
    float s = 0.f;
    #pragma unroll
    for(int m=0;m<64;m++){ float x = kr[lane*64+m]; s += x*x; }
    coefR[lane] = softplusf_(v[512+lane]) / fmaxf(sqrtf(s), EPSF);
  }
  if(wave == 0){
    const float* sw = scores + ((size_t)b*5 + 4)*(size_t)S_;
    float loc[32];
    #pragma unroll
    for(int j=0;j<32;j++) loc[j] = sw[lane + j*64];
    float mx = -INFINITY;
    #pragma unroll
    for(int j=0;j<32;j++) mx = fmaxf(mx, loc[j]);
    #pragma unroll
    for(int off=32; off; off>>=1) mx = fmaxf(mx, __shfl_down(mx, off));
    mx = __shfl(mx, 0);
    float sum = 0.f;
    #pragma unroll
    for(int j=0;j<32;j++) sum += expf(loc[j]-mx);
    #pragma unroll
    for(int off=32; off; off>>=1) sum += __shfl_down(sum, off);
    sum = __shfl(sum, 0);
    float invZ = 1.0f / sum;
    for(int p=0;p<8;p++){
      float bv = -INFINITY; int bi = 0x7fffffff;
      #pragma unroll
      for(int j=0;j<32;j++){            // strict > keeps smallest index in-lane
        float x = loc[j];
        if(x > bv){ bv = x; bi = j*64 + lane; }
      }
      #pragma unroll
      for(int off=32; off; off>>=1){
        float ov = __shfl_down(bv, off); int oi = __shfl_down(bi, off);
        if(ov > bv || (ov == bv && oi < bi)){ bv = ov; bi = oi; }
      }
      bv = __shfl(bv, 0); bi = __shfl(bi, 0);
      if(lane == 0){ widx[p] = bi; wval[p] = expf(bv-mx)*invZ; }
      if((bi & 63) == lane){
        int pos = bi >> 6;
        #pragma unroll
        for(int q=0;q<32;q++) if(q == pos) loc[q] = -INFINITY;
      }
    }
  }
  __syncthreads();

  // phase 3: rank-1 erase/add at the 8 write slots (only slots that change)
  #pragma unroll
  for(int p=0;p<2;p++){
    int idx = tid + p*256;              // 512 = 8 slots x 64 dims
    int j = idx >> 6, m = idx & 63;
    int s = widx[j];
    float w = wval[j];
    size_t ptr = ((size_t)b*64 + m)*(size_t)S_ + s;
    float old = memT[ptr];
    float x = old * (1.0f - w*er[m]) + w*ad[m];
    memT[ptr] = x;
    nv[j*64+m] = x;
  }
  __syncthreads();

  // phase 4: recompute read logits at the 8 updated slots
  if(wave < 4){
    #pragma unroll
    for(int q=0;q<2;q++){
      int sl = wave*2 + q;
      float x = nv[sl*64 + lane];
      float n2 = x*x;
      #pragma unroll
      for(int off=32; off; off>>=1) n2 += __shfl_down(n2, off);
      n2 = __shfl(n2, 0);
      float invmn = 1.0f / fmaxf(sqrtf(n2), EPSF);
      #pragma unroll
      for(int r=0;r<4;r++){
        float d = x * kr[r*64+lane];
        #pragma unroll
        for(int off=32; off; off>>=1) d += __shfl_down(d, off);
        if(lane == 0) fix[r*8+sl] = coefR[r] * d * invmn;
      }
    }
  }
  __syncthreads();

  // phase 5: read heads — one wave per head
  {
    const int r = wave;
    const float* sr = scores + ((size_t)b*5 + r)*(size_t)S_;
    float loc[32];
    #pragma unroll
    for(int j=0;j<32;j++) loc[j] = sr[lane + j*64];
    #pragma unroll
    for(int p=0;p<8;p++){               // patch updated slots
      int s = widx[p];
      if((s & 63) == lane){
        int pos = s >> 6; float f = fix[r*8+p];
        #pragma unroll
        for(int q=0;q<32;q++) if(q == pos) loc[q] = f;
      }
    }
    float mx = -INFINITY;
    #pragma unroll
    for(int j=0;j<32;j++) mx = fmaxf(mx, loc[j]);
    #pragma unroll
    for(int off=32; off; off>>=1) mx = fmaxf(mx, __shfl_down(mx, off));
    mx = __shfl(mx, 0);
    float sum = 0.f;
    #pragma unroll
    for(int j=0;j<32;j++) sum += expf(loc[j]-mx);
    #pragma unroll
    for(int off=32; off; off>>=1) sum += __shfl_down(sum, off);
    sum = __shfl(sum, 0);
    float invZ = 1.0f / sum;
    float acc = 0.f;                    // reads accumulator; lane == mem dim m
    const size_t rowp = ((size_t)b*64 + lane)*(size_t)S_;
    for(int p=0;p<8;p++){
      float bv = -INFINITY; int bi = 0x7fffffff;
      #pragma unroll
      for(int j=0;j<32;j++){
        float x = loc[j];
        if(x > bv){ bv = x; bi = j*64 + lane; }
      }
      #pragma unroll
      for(int off=32; off; off>>=1){
        float ov = __shfl_down(bv, off); int oi = __shfl_down(bi, off);
        if(ov > bv || (ov == bv && oi < bi)){ bv = ov; bi = oi; }
      }
      bv = __shfl(bv, 0); bi = __shfl(bi, 0);
      if((bi & 63) == lane){
        int pos = bi >> 6;
        #pragma unroll
        for(int q=0;q<32;q++) if(q == pos) loc[q] = -INFINITY;
      }
      float w = expf(bv-mx)*invZ;
      acc += w * memT[rowp + bi];       // new mem
    }
    readsv[r*64+lane] = acc;
  }
  __syncthreads();

  // phase 6: out[b,t,:] = vt + reads @ W_rd^T + b_rd
  {
    const int o = tid;
    float acc = v[o] + b_rd[o];
    #pragma unroll 4
    for(int k=0;k<256;k++) acc += readsv[k] * WrdT[k*256+o];
    out[((size_t)b*T_ + t)*(size_t)OUT_ + o] = acc;
  }
}

// ---------------- host ----------------
extern "C" void kernel_launch(void* const* d_in, const int* in_sizes, int n_in,
                              void* d_out, int out_size, void* d_ws, size_t ws_size,
                              hipStream_t stream)
{
  const float* x     = (const float*)d_in[0];
  const float* h0    = (const float*)d_in[1];
  const float* c0    = (const float*)d_in[2];
  const float* mem0  = (const float*)d_in[3];
  const float* W_ih  = (const float*)d_in[4];
  const float* W_hh  = (const float*)d_in[5];
  const float* b_ih  = (const float*)d_in[6];
  const float* b_hh  = (const float*)d_in[7];
  const float* W_out = (const float*)d_in[8];
  const float* b_out = (const float*)d_in[9];
  const float* W_rd  = (const float*)d_in[10];
  const float* b_rd  = (const float*)d_in[11];
  const float* W_head= (const float*)d_in[12];
  const float* b_head= (const float*)d_in[13];
  // d_in[14] = K (int) — fixed at 8 by the problem setup; hard-coded in k_heads.
  float* out = (float*)d_out;

  float* ws     = (float*)d_ws;
  float* memT   = ws;                    // 128*64*2048  = 16,777,216
  float* xg     = memT   + 16777216;     // 128*32*2048  =  8,388,608
  float* gparts = xg     + 8388608;      // 4*128*2048   =  1,048,576
  float* scores = gparts + 1048576;      // 128*5*2048   =  1,310,720
  float* vc     = scores + 1310720;      // 128*712      =     91,136
  float* h      = vc     + 91136;        // 128*512      =     65,536
  float* c      = h      + 65536;        // 128*512      =     65,536
  float* WrdT   = c      + 65536;        // 256*256      =     65,536
  const size_t need = (size_t)(27812864) * sizeof(float);
  if(ws_size < need) return;  // ~106 MB workspace required

  hipMemcpyAsync(h, h0, 65536*sizeof(float), hipMemcpyDeviceToDevice, stream);
  hipMemcpyAsync(c, c0, 65536*sizeof(float), hipMemcpyDeviceToDevice, stream);
  k_transpose_mem<<<dim3(128,64),256,0,stream>>>(mem0, memT);
  k_transpose_rd<<<256,256,0,stream>>>(W_rd, WrdT);
  // xg[b*T+t, :] = x @ W_ih^T + (b_ih+b_hh)  — hoisted out of the time loop
  k_gemm64<<<dim3(64,32,1),256,0,stream>>>(x,256, W_ih,256, xg,2048, 256, b_ih,b_hh);

  for(int t=0;t<T_;t++){
    // gates partials: h @ W_hh^T, split-K x4 for occupancy (256 blocks)
    k_gemm64<<<dim3(2,32,4),256,0,stream>>>(h,512, W_hh,512, gparts,2048, 128, nullptr,nullptr);
    k_lstm<<<256,256,0,stream>>>(xg, gparts, h, c, t);
    k_vtctrl<<<dim3(4,23),256,0,stream>>>(h, W_out,b_out, W_head,b_head, vc);
    k_scores<<<dim3(128,8),256,0,stream>>>(memT, vc, scores);
    k_heads<<<128,256,0,stream>>>(memT, scores, vc, WrdT, b_rd, out, t);
  }
}